// Round 1
// baseline (13460.210 us; speedup 1.0000x reference)
//
#include <hip/hip_runtime.h>

// Dims (fixed by the reference)
#define LAY 2
#define BATCH 64
#define TMAX 512
#define DIM 256
// packed weight slab: per (layer, matrix): 32 i-groups x 256 j x 8 k  bf16 = 65536 ushorts
#define SLAB 65536

__device__ __forceinline__ unsigned short f2bf(float f) {
    unsigned int u = __float_as_uint(f);
    unsigned int r = u + 0x7fffu + ((u >> 16) & 1u);  // RNE
    return (unsigned short)(r >> 16);
}
__device__ __forceinline__ float bflo(unsigned int u) { return __uint_as_float(u << 16); }
__device__ __forceinline__ float bfhi(unsigned int u) { return __uint_as_float(u & 0xffff0000u); }

// Weight prep: fp32 [L][256][256] row-major -> bf16 packed [(l*6+m)][i0][j][k], i = i0*8+k.
// Also zeroes d_out (runs before the main kernel on the same stream).
__global__ void prep_weights(const float* __restrict__ Wz, const float* __restrict__ Wr,
                             const float* __restrict__ Uz, const float* __restrict__ Ur,
                             const float* __restrict__ Wh, const float* __restrict__ Uh,
                             unsigned short* __restrict__ wp, float* __restrict__ out) {
    int idx = blockIdx.x * 256 + threadIdx.x;  // N = 12*65536 = 786432
    if (idx == 0) out[0] = 0.f;
    int k   = idx & 7;
    int j   = (idx >> 3) & 255;
    int i0  = (idx >> 11) & 31;
    int rem = idx >> 16;       // l*6 + m
    int m   = rem % 6;
    int l   = rem / 6;
    const float* src;
    switch (m) {
        case 0: src = Wz; break;
        case 1: src = Wr; break;
        case 2: src = Uz; break;
        case 3: src = Ur; break;
        case 4: src = Wh; break;
        default: src = Uh; break;
    }
    int i = i0 * 8 + k;
    float v = src[(l << 16) + (i << 8) + j];
    wp[idx] = f2bf(v);
}

// column-j dot over 256: weights bf16 packed (16B/lane coalesced), vec fp32 in LDS (broadcast reads)
__device__ __forceinline__ float dot256(const unsigned short* __restrict__ wslab, int j,
                                        const float* vec) {
    const uint4* wq = reinterpret_cast<const uint4*>(wslab) + j;
    const float4* vq = reinterpret_cast<const float4*>(vec);
    float a0 = 0.f, a1 = 0.f;
#pragma unroll
    for (int i0 = 0; i0 < 32; ++i0) {
        uint4 w = wq[i0 * 256];
        float4 v0 = vq[2 * i0];
        float4 v1 = vq[2 * i0 + 1];
        a0 = fmaf(bflo(w.x), v0.x, a0); a1 = fmaf(bfhi(w.x), v0.y, a1);
        a0 = fmaf(bflo(w.y), v0.z, a0); a1 = fmaf(bfhi(w.y), v0.w, a1);
        a0 = fmaf(bflo(w.z), v1.x, a0); a1 = fmaf(bfhi(w.z), v1.y, a1);
        a0 = fmaf(bflo(w.w), v1.z, a0); a1 = fmaf(bfhi(w.w), v1.w, a1);
    }
    return a0 + a1;
}

// One workgroup per batch element. 512 threads: gate0 = tid<256 (z / Wh / epilogue),
// gate1 = tid>=256 (r / Uh / x-prefetch). 3 barriers per layer-step.
__global__ __launch_bounds__(512) void gru_main(const float* __restrict__ x,
                                                const int* __restrict__ xlen,
                                                const float* __restrict__ xlab,
                                                const unsigned short* __restrict__ wp,
                                                const float* __restrict__ Wo,
                                                float* __restrict__ out) {
    __shared__ __align__(16) float xb[DIM];       // current x_t (fp32)
    __shared__ __align__(16) float s1f[2][DIM];   // S1 per layer
    __shared__ __align__(16) float rsf[DIM];      // r * S1
    __shared__ float zf[DIM];
    __shared__ float hpw[DIM];
    __shared__ float hpu[DIM];
    __shared__ float wo1[DIM];

    const int b = blockIdx.x;
    const int tid = threadIdx.x;
    const int j = tid & 255;
    const int gate = tid >> 8;  // wave-uniform (waves 0-3 vs 4-7)
    const int len = xlen[b];
    const float lab = xlab[b];
    float acc = 0.f;

    if (tid < 256) {
        s1f[0][tid] = 0.f;
        s1f[1][tid] = 0.f;
        wo1[tid] = Wo[2 * tid + 1];                       // column 1 of [256,2]
        xb[tid] = x[((size_t)b * TMAX + 0) * DIM + tid];  // x_0
    }
    __syncthreads();

    for (int t = 0; t < len; ++t) {
        for (int l = 0; l < 2; ++l) {
            const float* win = (l == 0) ? xb : s1f[0];  // layer input (hn0 already updated at l=1)
            const unsigned short* wl = wp + (size_t)l * 6 * SLAB;

            // ---- zr phase: gate0 -> z_j = sig(win@Wz_j + s@Uz_j); gate1 -> r, rs ----
            float d = dot256(wl + (size_t)gate * SLAB, j, win) +
                      dot256(wl + (size_t)(2 + gate) * SLAB, j, s1f[l]);
            float g = 1.f / (1.f + __expf(-d));
            if (gate == 0) zf[j] = g;
            else           rsf[j] = g * s1f[l][j];
            __syncthreads();

            // ---- h phase ----
            float xnext = 0.f;
            const bool pf = (l == 1) && (gate == 1) && (t + 1 < len);
            if (pf) xnext = x[((size_t)b * TMAX + t + 1) * DIM + j];  // latency hidden by the dot
            float hd = (gate == 0) ? dot256(wl + (size_t)4 * SLAB, j, win)
                                   : dot256(wl + (size_t)5 * SLAB, j, rsf);
            if (gate == 0) hpw[j] = hd;
            else           hpu[j] = hd;
            __syncthreads();

            // ---- epilogue: hn = (1-z)s + z*h  (S2 is dead code w.r.t. the loss) ----
            if (gate == 0) {
                float h = tanhf(hpw[j] + hpu[j]);
                float zz = zf[j];
                float s = s1f[l][j];
                s1f[l][j] = (1.f - zz) * s + zz * h;
            } else if (pf) {
                xb[j] = xnext;
            }
            __syncthreads();
        }
        // score = sigmoid(hn1 @ Wo[:,1]); wave 0 only, overlaps next step's zr phase (no conflicting writes)
        if (tid < 64) {
            float p = 0.f;
#pragma unroll
            for (int u = 0; u < 4; ++u) p = fmaf(s1f[1][tid * 4 + u], wo1[tid * 4 + u], p);
            p += __shfl_down(p, 32); p += __shfl_down(p, 16); p += __shfl_down(p, 8);
            p += __shfl_down(p, 4);  p += __shfl_down(p, 2);  p += __shfl_down(p, 1);
            if (tid == 0) {
                float sc = 1.f / (1.f + __expf(-p));
                float dd = lab - sc;
                acc = fmaf(dd, dd, acc);
            }
        }
    }
    if (tid == 0) atomicAdd(out, acc);
}

extern "C" void kernel_launch(void* const* d_in, const int* in_sizes, int n_in,
                              void* d_out, int out_size, void* d_ws, size_t ws_size,
                              hipStream_t stream) {
    const float* x    = (const float*)d_in[0];
    const int*   xlen = (const int*)d_in[1];
    const float* xlab = (const float*)d_in[2];
    const float* Wz   = (const float*)d_in[3];
    const float* Uz   = (const float*)d_in[4];
    const float* Wr   = (const float*)d_in[5];
    const float* Ur   = (const float*)d_in[6];
    const float* Wh   = (const float*)d_in[7];
    const float* Uh   = (const float*)d_in[8];
    const float* Wo   = (const float*)d_in[9];
    float* out = (float*)d_out;
    unsigned short* wp = (unsigned short*)d_ws;  // 786432 ushorts = 1.5 MB

    // ws is re-poisoned before every timed call -> rebuild packed weights every call.
    prep_weights<<<3072, 256, 0, stream>>>(Wz, Wr, Uz, Ur, Wh, Uh, wp, out);
    gru_main<<<BATCH, 512, 0, stream>>>(x, xlen, xlab, wp, Wo, out);
}